// Round 2
// baseline (5327.515 us; speedup 1.0000x reference)
//
#include <hip/hip_runtime.h>
#include <hip/hip_bf16.h>

#define PX 9216      // 96*96
#define LL 9216
#define HALF_L 4608
#define CCH 64       // emitted steps per chunk
#define NCHUNK 144   // 9216/64
#define WARM_BF 256
#define WARM_F32 512
#define NITER 50
#define CB 4         // conv batch chunk

// ws offsets (floats)
#define OFF_WC   0        // 32 scaled GRU consts
#define OFF_FLAG 32
#define OFF_HL   40       // 128
#define OFF_W1   192      // 144
#define OFF_B1   336      // 16
#define OFF_W2   384      // 4608
#define OFF_B2   4992     // 32
#define OFF_W3   5024     // 864
#define OFF_B3   5888     // 3
#define OFF_KX   5896     // 9
#define OFF_KY   5908     // 9
#define OFF_GRAY 8192     // 294912
#define OFF_G    303104   // 294912
#define OFF_MK   598016   // 294912
#define OFF_X0   892928   // 589824 + 64 pad
#define OFF_YA   1482816  // 589824 + 64 pad
#define OFF_YB   2072704  // 589824 + 64 pad
#define OFF_C1   2662592  // CB*16*9216 = 589824
#define OFF_C2   3252416  // CB*32*9216 = 1179648 ; end 4432064 floats = 17.7 MB

static __device__ __forceinline__ float ldv(const void* p, long i, bool isb) {
    return isb ? __bfloat162float(((const __hip_bfloat16*)p)[i])
               : ((const float*)p)[i];
}

__global__ __launch_bounds__(256) void k_prep(
    float* __restrict__ ws, const void* img,
    const void* w1, const void* b1, const void* w2, const void* b2,
    const void* w3, const void* b3, const void* kx, const void* ky,
    const void* wih, const void* whh, const void* bih, const void* bhh)
{
    __shared__ float s_isb;
    int t = threadIdx.x;
    if (t == 0) {
        const unsigned short* u16 = (const unsigned short*)img;
        int cnt = 0;
        for (int k = 0; k < 256; ++k) {
            unsigned short u = u16[k];
            int e = (u >> 7) & 0xFF;
            bool ok = (u == 0) || (((u & 0x8000) == 0) && e >= 0x20 && e <= 0x7E);
            cnt += ok ? 1 : 0;
        }
        s_isb = (cnt >= 224) ? 1.f : 0.f;
        ws[OFF_FLAG] = s_isb;
    }
    __syncthreads();
    bool isb = s_isb > 0.5f;

    for (int i = t; i < 144; i += 256) { int co = i/9, tap = i%9; ws[OFF_W1 + tap*16 + co] = ldv(w1,i,isb); }
    for (int i = t; i < 16; i += 256) ws[OFF_B1+i] = ldv(b1,i,isb);
    for (int i = t; i < 4608; i += 256) { int co = i/144, r = i%144, ci = r/9, tap = r%9;
        ws[OFF_W2 + (ci*9+tap)*32 + co] = ldv(w2,i,isb); }
    for (int i = t; i < 32; i += 256) ws[OFF_B2+i] = ldv(b2,i,isb);
    for (int i = t; i < 864; i += 256) { int o = i/288, r = i%288, ci = r/9, tap = r%9;
        ws[OFF_W3 + (ci*9+tap)*3 + o] = ldv(w3,i,isb); }
    for (int i = t; i < 3; i += 256) ws[OFF_B3+i] = ldv(b3,i,isb);
    for (int i = t; i < 9; i += 256) { ws[OFF_KX+i] = ldv(kx,i,isb); ws[OFF_KY+i] = ldv(ky,i,isb); }
    for (int i = t; i < 128; i += 256) ws[OFF_HL+i] = 0.f;
    if (t == 0) {
        const float C1 = 1.4426950408889634f;
        for (int g = 0; g < 4; ++g) {   // r,z gates: scale by -log2e
            ws[OFF_WC + g*2+0]     = -C1*ldv(wih, g*2+0, isb);
            ws[OFF_WC + g*2+1]     = -C1*ldv(wih, g*2+1, isb);
            ws[OFF_WC + 8 + g*2+0] = -C1*ldv(whh, g*2+0, isb);
            ws[OFF_WC + 8 + g*2+1] = -C1*ldv(whh, g*2+1, isb);
            ws[OFF_WC + 16 + g]    = -C1*(ldv(bih,g,isb)+ldv(bhh,g,isb));
        }
        for (int j = 0; j < 2; ++j) {   // n gate: tanh(t)=1-2/(1+2^(2*log2e*t))
            int g = 4+j;
            ws[OFF_WC + 20 + j*2+0] = 2.f*C1*ldv(wih, g*2+0, isb);
            ws[OFF_WC + 20 + j*2+1] = 2.f*C1*ldv(wih, g*2+1, isb);
            ws[OFF_WC + 24 + j*2+0] = 2.f*C1*ldv(whh, g*2+0, isb);
            ws[OFF_WC + 24 + j*2+1] = 2.f*C1*ldv(whh, g*2+1, isb);
            ws[OFF_WC + 28 + j]     = 2.f*C1*ldv(bih, g, isb);
            ws[OFF_WC + 30 + j]     = 2.f*C1*ldv(bhh, g, isb);
        }
    }
}

__global__ __launch_bounds__(256) void k_gray(const void* __restrict__ img,
                                              float* __restrict__ ws)
{
    bool isb = ws[OFF_FLAG] > 0.5f;
    int t = blockIdx.x*256 + threadIdx.x;
    int b = t / PX, p = t - b*PX;
    long base = (long)b*3*PX;
    float r  = ldv(img, base + p, isb);
    float g  = ldv(img, base + PX + p, isb);
    float bl = ldv(img, base + 2*PX + p, isb);
    ws[OFF_GRAY + t] = fmaf(0.2989f, r, fmaf(0.587f, g, 0.114f*bl));
}

__global__ __launch_bounds__(256) void k_sobel(float* __restrict__ ws)
{
    int t = blockIdx.x*256 + threadIdx.x;
    int b = t / PX, p = t - b*PX;
    int y = p / 96, x = p - y*96;
    const float* g = ws + OFF_GRAY + b*PX;
    float gx = 0.f, gy = 0.f;
    #pragma unroll
    for (int dy = 0; dy < 3; ++dy)
    #pragma unroll
    for (int dx = 0; dx < 3; ++dx) {
        int yy = y+dy-1, xx = x+dx-1;
        float v = (yy >= 0 && yy < 96 && xx >= 0 && xx < 96) ? g[yy*96+xx] : 0.f;
        gx = fmaf(v, ws[OFF_KX + dy*3+dx], gx);
        gy = fmaf(v, ws[OFF_KY + dy*3+dx], gy);
    }
    ws[OFF_G + t] = sqrtf(fmaf(gx, gx, gy*gy));
}

__global__ __launch_bounds__(256) void k_conv1(float* __restrict__ ws, int b0)
{
    int t = blockIdx.x*256 + threadIdx.x;   // CB*9216 threads
    int bb = t / PX, p = t - bb*PX;
    int y = p / 96, x = p - y*96;
    const float* g = ws + OFF_GRAY + (b0+bb)*PX;
    float acc[16];
    #pragma unroll
    for (int co = 0; co < 16; ++co) acc[co] = 0.f;
    #pragma unroll
    for (int dy = 0; dy < 3; ++dy)
    #pragma unroll
    for (int dx = 0; dx < 3; ++dx) {
        int yy = y+dy-1, xx = x+dx-1;
        float v = (yy >= 0 && yy < 96 && xx >= 0 && xx < 96) ? g[yy*96+xx] : 0.f;
        const float* w = ws + OFF_W1 + (dy*3+dx)*16;
        #pragma unroll
        for (int co = 0; co < 16; ++co) acc[co] = fmaf(v, w[co], acc[co]);
    }
    float* o = ws + OFF_C1 + bb*16*PX + p;
    #pragma unroll
    for (int co = 0; co < 16; ++co)
        o[co*PX] = fmaxf(acc[co] + ws[OFF_B1+co], 0.f);
}

__global__ __launch_bounds__(256) void k_conv2(float* __restrict__ ws)
{
    __shared__ float tile[16*324];   // 16 ci x 18x18 halo
    int bb = blockIdx.x / 36;
    int tI = blockIdx.x % 36;
    int ty0 = (tI / 6) * 16, tx0 = (tI % 6) * 16;
    int t = threadIdx.x;
    for (int i = t; i < 5184; i += 256) {
        int ci = i / 324, r = i - ci*324;
        int yy = r / 18, xx = r - yy*18;
        int gy = ty0 + yy - 1, gx = tx0 + xx - 1;
        float v = 0.f;
        if (gy >= 0 && gy < 96 && gx >= 0 && gx < 96)
            v = ws[OFF_C1 + (bb*16 + ci)*PX + gy*96 + gx];
        tile[i] = v;
    }
    __syncthreads();
    int ty = t / 16, tx = t - (t/16)*16;
    float acc[32];
    #pragma unroll
    for (int co = 0; co < 32; ++co) acc[co] = 0.f;
    for (int ci = 0; ci < 16; ++ci) {
        #pragma unroll
        for (int dy = 0; dy < 3; ++dy)
        #pragma unroll
        for (int dx = 0; dx < 3; ++dx) {
            float v = tile[ci*324 + (ty+dy)*18 + (tx+dx)];
            const float* w = ws + OFF_W2 + (ci*9 + dy*3 + dx)*32;
            #pragma unroll
            for (int co = 0; co < 32; ++co) acc[co] = fmaf(v, w[co], acc[co]);
        }
    }
    int p = (ty0+ty)*96 + tx0 + tx;
    float* o = ws + OFF_C2 + bb*32*PX + p;
    #pragma unroll
    for (int co = 0; co < 32; ++co)
        o[co*PX] = fmaxf(acc[co] + ws[OFF_B2+co], 0.f);
}

__global__ __launch_bounds__(256) void k_conv3(float* __restrict__ ws, int b0)
{
    int t = blockIdx.x*256 + threadIdx.x;
    int bb = t / PX, p = t - bb*PX;
    int y = p / 96, x = p - y*96;
    float a0 = 0.f, a1 = 0.f, a2 = 0.f;
    for (int ci = 0; ci < 32; ++ci) {
        const float* s = ws + OFF_C2 + (bb*32 + ci)*PX;
        #pragma unroll
        for (int dy = 0; dy < 3; ++dy)
        #pragma unroll
        for (int dx = 0; dx < 3; ++dx) {
            int yy = y+dy-1, xx = x+dx-1;
            float v = (yy >= 0 && yy < 96 && xx >= 0 && xx < 96) ? s[yy*96+xx] : 0.f;
            const float* w = ws + OFF_W3 + (ci*9 + dy*3 + dx)*3;
            a0 = fmaf(v, w[0], a0);
            a1 = fmaf(v, w[1], a1);
            a2 = fmaf(v, w[2], a2);
        }
    }
    a0 += ws[OFF_B3+0]; a1 += ws[OFF_B3+1]; a2 += ws[OFF_B3+2];
    int m = 0; float best = a0;
    if (a1 > best) { best = a1; m = 1; }
    if (a2 > best) { m = 2; }
    ws[OFF_MK + (b0+bb)*PX + p] = (float)m;
}

__global__ __launch_bounds__(256) void k_pack(float* __restrict__ ws)
{
    int t = blockIdx.x*256 + threadIdx.x;
    int b = t / LL, l = t - b*LL;
    float v0, v1;
    if (l < HALF_L) {
        const float* m = ws + OFF_MK + b*PX + 2*l;
        v0 = m[0]; v1 = m[1];
    } else {
        const float* g = ws + OFF_G + b*PX + 2*(l - HALF_L);
        v0 = g[0]; v1 = g[1];
    }
    ((float2*)(ws + OFF_X0))[b*LL + l] = make_float2(v0, v1);
}

__global__ __launch_bounds__(256) void k_gru(const float* __restrict__ ws,
                                             const float2* __restrict__ src,
                                             float2* __restrict__ dst,
                                             const float* __restrict__ hlin,
                                             float* __restrict__ hlout)
{
    int i = blockIdx.x*256 + threadIdx.x;   // 4608 threads exactly
    int b = i / NCHUNK, c = i - b*NCHUNK;
    int warm = (ws[OFF_FLAG] > 0.5f) ? WARM_BF : WARM_F32;
    float kk[32];
    #pragma unroll
    for (int j = 0; j < 32; ++j) kk[j] = ws[OFF_WC + j];

    int emit = c * CCH;
    int end  = emit + CCH;
    int start = emit - warm;
    float h0, h1;
    if (start <= 0) { start = 0; h0 = hlin[2*b]; h1 = hlin[2*b+1]; }
    else            { h0 = 0.f; h1 = 0.f; }

    const float2* s = src + b*LL;
    float2*       d = dst + b*LL;

    auto STEP = [&](float xa, float xb) {
        float ar0 = fmaf(kk[8],  h0, fmaf(kk[9],  h1, fmaf(kk[0], xa, fmaf(kk[1], xb, kk[16]))));
        float ar1 = fmaf(kk[10], h0, fmaf(kk[11], h1, fmaf(kk[2], xa, fmaf(kk[3], xb, kk[17]))));
        float az0 = fmaf(kk[12], h0, fmaf(kk[13], h1, fmaf(kk[4], xa, fmaf(kk[5], xb, kk[18]))));
        float az1 = fmaf(kk[14], h0, fmaf(kk[15], h1, fmaf(kk[6], xa, fmaf(kk[7], xb, kk[19]))));
        float er0 = __builtin_amdgcn_exp2f(fminf(ar0, 60.f));
        float er1 = __builtin_amdgcn_exp2f(fminf(ar1, 60.f));
        float ez0 = __builtin_amdgcn_exp2f(fminf(az0, 60.f));
        float ez1 = __builtin_amdgcn_exp2f(fminf(az1, 60.f));
        float tr0 = 1.f + er0, tr1 = 1.f + er1;
        float tz0 = 1.f + ez0, tz1 = 1.f + ez1;
        float iR = __builtin_amdgcn_rcpf(tr0*tr1);
        float iZ = __builtin_amdgcn_rcpf(tz0*tz1);
        float r0 = iR*tr1, r1 = iR*tr0;
        float z0 = iZ*tz1, z1 = iZ*tz0;
        float hn0 = fmaf(kk[24], h0, fmaf(kk[25], h1, kk[30]));
        float hn1 = fmaf(kk[26], h0, fmaf(kk[27], h1, kk[31]));
        float u0 = fmaf(r0, hn0, fmaf(kk[20], xa, fmaf(kk[21], xb, kk[28])));
        float u1 = fmaf(r1, hn1, fmaf(kk[22], xa, fmaf(kk[23], xb, kk[29])));
        float e0 = __builtin_amdgcn_exp2f(fminf(u0, 60.f));
        float e1 = __builtin_amdgcn_exp2f(fminf(u1, 60.f));
        float s0 = 1.f + e0, s1 = 1.f + e1;
        float iN = __builtin_amdgcn_rcpf(s0*s1);
        float m2 = -2.f*iN;
        float n0 = fmaf(m2, s1, 1.f);
        float n1 = fmaf(m2, s0, 1.f);
        h0 = fmaf(z0, h0 - n0, n0);
        h1 = fmaf(z1, h1 - n1, n1);
    };

    float4 p0 = *(const float4*)(s + start);
    float4 p1 = *(const float4*)(s + start + 2);
    for (int l = start; l < end; l += 4) {
        float4 q0 = *(const float4*)(s + l + 4);   // padded buffers: safe overread
        float4 q1 = *(const float4*)(s + l + 6);
        STEP(p0.x, p0.y); float y00 = h0, y01 = h1;
        STEP(p0.z, p0.w); float y10 = h0, y11 = h1;
        STEP(p1.x, p1.y); float y20 = h0, y21 = h1;
        STEP(p1.z, p1.w);
        if (l >= emit) {
            *(float4*)(d + l)     = make_float4(fmaxf(y00,0.f), fmaxf(y01,0.f),
                                                fmaxf(y10,0.f), fmaxf(y11,0.f));
            *(float4*)(d + l + 2) = make_float4(fmaxf(y20,0.f), fmaxf(y21,0.f),
                                                fmaxf(h0,0.f),  fmaxf(h1,0.f));
        }
        p0 = q0; p1 = q1;
    }
    if (c == NCHUNK-1) { hlout[2*b] = h0; hlout[2*b+1] = h1; }
}

__global__ __launch_bounds__(256) void k_out(const float* __restrict__ ws,
                                             const void* __restrict__ ow,
                                             const void* __restrict__ ob,
                                             void* __restrict__ out)
{
    bool isb = ws[OFF_FLAG] > 0.5f;
    int t = blockIdx.x*256 + threadIdx.x;
    int b = t / PX, p = t - b*PX;
    float2 v = ((const float2*)(ws + OFF_YB))[b*LL + p];
    #pragma unroll
    for (int o = 0; o < 3; ++o) {
        float w0 = ldv(ow, o*2,   isb);
        float w1 = ldv(ow, o*2+1, isb);
        float bi = ldv(ob, o,     isb);
        float r = fmaf(v.y, w1, fmaf(v.x, w0, bi));
        long idx = (long)(b*3 + o)*PX + p;
        if (isb) ((__hip_bfloat16*)out)[idx] = __float2bfloat16(r);
        else     ((float*)out)[idx] = r;
    }
}

extern "C" void kernel_launch(void* const* d_in, const int* in_sizes, int n_in,
                              void* d_out, int out_size, void* d_ws, size_t ws_size,
                              hipStream_t stream)
{
    (void)in_sizes; (void)n_in; (void)out_size; (void)ws_size;
    float* ws = (float*)d_ws;
    const void* img = d_in[0];
    const void* kx  = d_in[1];
    const void* ky  = d_in[2];
    const void* w1  = d_in[3];
    const void* b1  = d_in[4];
    const void* w2  = d_in[5];
    const void* b2  = d_in[6];
    const void* w3  = d_in[7];
    const void* b3  = d_in[8];
    const void* wih = d_in[9];
    const void* whh = d_in[10];
    const void* bih = d_in[11];
    const void* bhh = d_in[12];
    const void* owp = d_in[13];
    const void* obp = d_in[14];

    k_prep<<<1, 256, 0, stream>>>(ws, img, w1,b1,w2,b2,w3,b3,kx,ky,wih,whh,bih,bhh);
    k_gray<<<1152, 256, 0, stream>>>(img, ws);
    k_sobel<<<1152, 256, 0, stream>>>(ws);
    for (int q = 0; q < 8; ++q) {          // batch chunks of CB=4
        k_conv1<<<144, 256, 0, stream>>>(ws, q*CB);
        k_conv2<<<144, 256, 0, stream>>>(ws);
        k_conv3<<<144, 256, 0, stream>>>(ws, q*CB);
    }
    k_pack<<<1152, 256, 0, stream>>>(ws);

    const float2* x0 = (const float2*)(ws + OFF_X0);
    float2* ya = (float2*)(ws + OFF_YA);
    float2* yb = (float2*)(ws + OFF_YB);
    float* hl = ws + OFF_HL;
    for (int it = 0; it < NITER; ++it) {
        const float2* src = (it == 0) ? x0 : ((it & 1) ? (const float2*)ya
                                                       : (const float2*)yb);
        float2* dst = (it & 1) ? yb : ya;
        k_gru<<<18, 256, 0, stream>>>(ws, src, dst,
                                      hl + (it & 1)*64, hl + ((it + 1) & 1)*64);
    }
    k_out<<<1152, 256, 0, stream>>>(ws, owp, obp, d_out);
}